// Round 6
// baseline (1895.935 us; speedup 1.0000x reference)
//
#include <hip/hip_runtime.h>
#include <stdint.h>

typedef unsigned short u16;
typedef unsigned int u32;
typedef __attribute__((ext_vector_type(8))) short short8;   // 8 bf16 (4 VGPR)
typedef __attribute__((ext_vector_type(4))) float f32x4;

#define NTHR 384
#define K2E16 0.09016844005556021f   /* log2(e)/16 : 1/sqrt(256) folded into exp2 */

// LDS overlays (all start at 0, live at disjoint phases):
//   kwL  [96][304B]  29184  (P1..P2)
//   encL [96][256B]  24576  (enc K-half staging, P3..P6)
//   fragL col-half   24576  (P7..P10)
// bvoL f32[256] at 29184. Total 30208 -> 5 blocks LDS-wise; regs cap 4.
#define KW_STRIDE 304
#define BVO_OFF   29184
#define LDS_TOTAL 30208

static __device__ __forceinline__ u16 f2bf(float f) {
  union { float f; u32 u; } v; v.f = f;
  u32 r = v.u + 0x7FFFu + ((v.u >> 16) & 1u);   // RNE
  return (u16)(r >> 16);
}
static __device__ __forceinline__ float bf2f(u16 x) {
  union { u32 u; float f; } v; v.u = ((u32)x) << 16; return v.f;
}

// ---------------------------------------------------------------------------
// K0: weight prep.
//  - WkqE[de][c]: c<128 -> sum_h Wk[de][h]*Wq[c][h]; c==128 -> Wk[de]·bq;
//                 129..143 -> 0. bf16 MFMA B-frags (K=128, 9 col-tiles).
//    (bk-dependent score terms are constant over p -> cancel in softmax.)
//  - WvoF = bf16 B-frags of Wv@Wo (K=256, 16 col-tiles); bvo = bv@Wo + bo.
// ---------------------------------------------------------------------------
__global__ __launch_bounds__(256) void k_setup(
    const float* __restrict__ Wq, const float* __restrict__ Wk,
    const float* __restrict__ Wv, const float* __restrict__ Wo,
    const float* __restrict__ bq,
    const float* __restrict__ bv, const float* __restrict__ bo,
    u16* __restrict__ WkqF, u16* __restrict__ WvoF, float* __restrict__ bvo) {
  const int ci = blockIdx.x;   // k-row
  const int co = threadIdx.x;  // col
  float acc = 0.f;
  for (int h = 0; h < 256; ++h) acc += Wv[ci*256 + h] * Wo[h*256 + co];
  const int idxv = (((ci>>5)*16 + (co>>4))*64 + (((ci>>3)&3)*16 + (co&15)))*8 + (ci&7);
  WvoF[idxv] = f2bf(acc);
  if (ci < 128 && co < 144) {
    float a = 0.f;
    if (co < 128)       { for (int h = 0; h < 256; ++h) a += Wk[ci*256 + h] * Wq[co*256 + h]; }
    else if (co == 128) { for (int h = 0; h < 256; ++h) a += Wk[ci*256 + h] * bq[h]; }
    const int idx = (((ci>>5)*9 + (co>>4))*64 + (((ci>>3)&3)*16 + (co&15)))*8 + (ci&7);
    WkqF[idx] = f2bf(a);
  }
  if (ci == 0) {
    float a2 = 0.f;
    for (int h = 0; h < 256; ++h) a2 += bv[h] * Wo[h*256 + co];
    bvo[co] = a2 + bo[co];
  }
}

// ---------------------------------------------------------------------------
// K2 fused, grid (1024, 8), 6 waves, 30208B LDS, VGPR<=85 -> 4 blocks/CU.
//   P1: KW = bf16(senc_rows)@WkqE -> kwL (senc/sdec frags DIRECT from global)
//   P2: scoresT = KW[:,0:128]@sdecT (+col128), softmax, af (1/sum folded)
//   P3-P6: enc2 = bf16(enc)@Wvo, acc2[16] in regs; enc staged through encL
//          in two K-halves (overlays dead kwL)
//   P7-P10: acc2 -> sigma B-frags in fragL (two col-halves); PV + store
// ---------------------------------------------------------------------------
__global__ __launch_bounds__(NTHR, 6) void k_attn(
    const float* __restrict__ sdec, const float* __restrict__ senc,
    const float* __restrict__ enc,
    const u16* __restrict__ WkqF, const u16* __restrict__ WvoF,
    const float* __restrict__ bvo, float* __restrict__ out) {
  extern __shared__ char smem[];
  char* kwL   = smem;                  // 29184, P1..P2
  char* encL  = smem;                  // 24576, P3..P6
  char* fragL = smem;                  // 24576, P7..P10
  float* bvoL = (float*)(smem + BVO_OFF);

  const int n = blockIdx.x, b = blockIdx.y;
  const int tid = threadIdx.x, wave = tid >> 6, lane = tid & 63;
  const int g = lane >> 4, c15 = lane & 15;
  const int prow = 16*wave + c15;      // this wave's A-fragment row

  // ---- issue sdec + senc fragment loads (wave-own rows; 16 deep) ----
  const float* sdp = sdec + ((size_t)((b*96 + prow)*1024 + n))*128 + 8*g;
  const float* sep = senc + ((size_t)((b*96 + prow)*1024 + n))*128 + 8*g;
  float4 sdv[4][2], sev[4][2];
  #pragma unroll
  for (int kt = 0; kt < 4; ++kt) {
    sev[kt][0] = *(const float4*)(sep + 32*kt);
    sev[kt][1] = *(const float4*)(sep + 32*kt + 4);
    sdv[kt][0] = *(const float4*)(sdp + 32*kt);
    sdv[kt][1] = *(const float4*)(sdp + 32*kt + 4);
  }
  if (tid < 256) bvoL[tid] = bvo[tid];

  short8 sef[4], sdf[4];
  #pragma unroll
  for (int kt = 0; kt < 4; ++kt) {
    union { u32 u[4]; short8 v; } cv;
    cv.u[0] = (u32)f2bf(sev[kt][0].x) | ((u32)f2bf(sev[kt][0].y) << 16);
    cv.u[1] = (u32)f2bf(sev[kt][0].z) | ((u32)f2bf(sev[kt][0].w) << 16);
    cv.u[2] = (u32)f2bf(sev[kt][1].x) | ((u32)f2bf(sev[kt][1].y) << 16);
    cv.u[3] = (u32)f2bf(sev[kt][1].z) | ((u32)f2bf(sev[kt][1].w) << 16);
    sef[kt] = cv.v;
  }
  #pragma unroll
  for (int kt = 0; kt < 4; ++kt) {
    union { u32 u[4]; short8 v; } cv;
    cv.u[0] = (u32)f2bf(sdv[kt][0].x) | ((u32)f2bf(sdv[kt][0].y) << 16);
    cv.u[1] = (u32)f2bf(sdv[kt][0].z) | ((u32)f2bf(sdv[kt][0].w) << 16);
    cv.u[2] = (u32)f2bf(sdv[kt][1].x) | ((u32)f2bf(sdv[kt][1].y) << 16);
    cv.u[3] = (u32)f2bf(sdv[kt][1].z) | ((u32)f2bf(sdv[kt][1].w) << 16);
    sdf[kt] = cv.v;
  }

  // ---- P1: KW rows [16w,16w+16) x 144 = senc_rows @ WkqE -> kwL ----
  {
    f32x4 acc[9];
    #pragma unroll
    for (int nt = 0; nt < 9; ++nt) acc[nt] = (f32x4)0.f;
    #pragma unroll
    for (int kt = 0; kt < 4; ++kt) {
      #pragma unroll
      for (int nt = 0; nt < 9; ++nt) {
        const short8 bf = *(const short8*)(WkqF + (size_t)((kt*9 + nt)*64 + lane)*8);
        acc[nt] = __builtin_amdgcn_mfma_f32_16x16x32_bf16(sef[kt], bf, acc[nt], 0, 0, 0);
      }
    }
    #pragma unroll
    for (int nt = 0; nt < 9; ++nt) {
      #pragma unroll
      for (int r = 0; r < 4; ++r)
        *(u16*)(kwL + (16*wave + 4*g + r)*KW_STRIDE + 2*(c15 + 16*nt)) = f2bf(acc[nt][r]);
    }
  }
  __syncthreads();   // bar1: kwL complete

  // ---- P2: scoresT = KW[:,0:128] @ sdecT for this wave's 16 q-cols ----
  f32x4 sac[6];
  #pragma unroll
  for (int pt = 0; pt < 6; ++pt) sac[pt] = (f32x4)0.f;
  #pragma unroll
  for (int kt = 0; kt < 4; ++kt) {
    #pragma unroll
    for (int pt = 0; pt < 6; ++pt) {
      const short8 kf = *(const short8*)(kwL + (16*pt + c15)*KW_STRIDE + 16*g + 64*kt);
      sac[pt] = __builtin_amdgcn_mfma_f32_16x16x32_bf16(kf, sdf[kt], sac[pt], 0, 0, 0);
    }
  }
  #pragma unroll
  for (int pt = 0; pt < 6; ++pt)
    #pragma unroll
    for (int r = 0; r < 4; ++r)
      sac[pt][r] += bf2f(*(const u16*)(kwL + (16*pt + 4*g + r)*KW_STRIDE + 256));

  // ---- softmax over p; q = 16w + c15 lives in lanes {l, l^16, l^32} ----
  float m = sac[0][0];
  #pragma unroll
  for (int pt = 0; pt < 6; ++pt)
    #pragma unroll
    for (int r = 0; r < 4; ++r) m = fmaxf(m, sac[pt][r]);
  m = fmaxf(m, __shfl_xor(m, 16));
  m = fmaxf(m, __shfl_xor(m, 32));
  float s = 0.f;
  #pragma unroll
  for (int pt = 0; pt < 6; ++pt)
    #pragma unroll
    for (int r = 0; r < 4; ++r) {
      const float e = exp2f((sac[pt][r] - m) * K2E16);
      sac[pt][r] = e; s += e;
    }
  s += __shfl_xor(s, 16);
  s += __shfl_xor(s, 32);
  const float rs = 1.f / s;

  short8 af[3];
  #pragma unroll
  for (int kb = 0; kb < 3; ++kb) {
    union { u32 u[4]; short8 v; } cv;
    cv.u[0] = (u32)f2bf(sac[2*kb][0]*rs)   | ((u32)f2bf(sac[2*kb][1]*rs)   << 16);
    cv.u[1] = (u32)f2bf(sac[2*kb][2]*rs)   | ((u32)f2bf(sac[2*kb][3]*rs)   << 16);
    cv.u[2] = (u32)f2bf(sac[2*kb+1][0]*rs) | ((u32)f2bf(sac[2*kb+1][1]*rs) << 16);
    cv.u[3] = (u32)f2bf(sac[2*kb+1][2]*rs) | ((u32)f2bf(sac[2*kb+1][3]*rs) << 16);
    af[kb] = cv.v;
  }
  __syncthreads();   // bar2: kwL reads done -> encL region free

  f32x4 acc2[16];
  #pragma unroll
  for (int nt = 0; nt < 16; ++nt) acc2[nt] = (f32x4)0.f;

  // ---- P3/P5 staging + P4/P6 accumulate, two K-halves ----
  #pragma unroll
  for (int half = 0; half < 2; ++half) {
    // stage encL with this K-half (96 rows x 128 ch f32 -> 256B bf16, swizzled)
    for (int i = wave; i < 48; i += 6) {
      const int r = 2*i + (lane >> 5);
      const int cl = lane & 31;
      const float4 v = *(const float4*)(enc + ((size_t)((b*96 + r)*1024 + n))*256 + half*128 + cl*4);
      u32 lo = (u32)f2bf(v.x) | ((u32)f2bf(v.y) << 16);
      u32 hi = (u32)f2bf(v.z) | ((u32)f2bf(v.w) << 16);
      u32* d = (u32*)(encL + r*256 + ((cl*8) ^ ((r & 7) << 4)));
      d[0] = lo; d[1] = hi;
    }
    __syncthreads();   // bar3/bar5: encL half staged
    #pragma unroll
    for (int ktl = 0; ktl < 4; ++ktl) {
      const short8 a = *(const short8*)(encL + prow*256 + ((16*g + 64*ktl) ^ ((prow & 7) << 4)));
      const int kt = half*4 + ktl;
      #pragma unroll
      for (int nt = 0; nt < 16; ++nt) {
        const short8 bf = *(const short8*)(WvoF + (size_t)((kt*16 + nt)*64 + lane)*8);
        acc2[nt] = __builtin_amdgcn_mfma_f32_16x16x32_bf16(a, bf, acc2[nt], 0, 0, 0);
      }
    }
    __syncthreads();   // bar4/bar6: encL reads done (next stage / fragL may clobber)
  }

  // ---- P7..P10: two col-halves: sigma-frag exchange + PV + store ----
  const int kb0 = wave >> 1, hi = wave & 1;
  #pragma unroll
  for (int half = 0; half < 2; ++half) {
    #pragma unroll
    for (int ntl = 0; ntl < 8; ++ntl) {
      uint2 o;
      const f32x4 v = acc2[half*8 + ntl];
      o.x = (u32)f2bf(v[0]) | ((u32)f2bf(v[1]) << 16);
      o.y = (u32)f2bf(v[2]) | ((u32)f2bf(v[3]) << 16);
      *(uint2*)(fragL + (((ntl*3 + kb0)*64 + lane) << 4) + hi*8) = o;
    }
    __syncthreads();   // bar7/bar9: fragL half complete
    #pragma unroll
    for (int ntl = 0; ntl < 8; ++ntl) {
      f32x4 oa = (f32x4)0.f;
      #pragma unroll
      for (int kb = 0; kb < 3; ++kb) {
        const short8 ef = *(const short8*)(fragL + (((ntl*3 + kb)*64 + lane) << 4));
        oa = __builtin_amdgcn_mfma_f32_16x16x32_bf16(af[kb], ef, oa, 0, 0, 0);
      }
      const int c = c15 + 16*(half*8 + ntl);
      const float bz = bvoL[c];
      #pragma unroll
      for (int r = 0; r < 4; ++r) {
        const int qi = 16*wave + 4*g + r;
        out[((size_t)((b*96 + qi)*1024 + n))*256 + c] = oa[r] + bz;
      }
    }
    if (half == 0) __syncthreads();   // bar8: PV-A reads done before fragL-B writes
  }
}

// ---------------------------------------------------------------------------
extern "C" void kernel_launch(void* const* d_in, const int* in_sizes, int n_in,
                              void* d_out, int out_size, void* d_ws, size_t ws_size,
                              hipStream_t stream) {
  const float* enc     = (const float*)d_in[0];
  const float* ste_enc = (const float*)d_in[1];
  const float* ste_dec = (const float*)d_in[2];
  const float* Wq = (const float*)d_in[3];
  const float* bq = (const float*)d_in[4];
  const float* Wk = (const float*)d_in[5];
  const float* Wv = (const float*)d_in[7];
  const float* bv = (const float*)d_in[8];
  const float* Wo = (const float*)d_in[9];
  const float* bo = (const float*)d_in[10];
  float* out = (float*)d_out;

  u16*   WkqF = (u16*)d_ws;                               // 36864 B
  u16*   WvoF = (u16*)((char*)d_ws + 36864);              // 131072 B -> 167936
  float* bvo  = (float*)((char*)d_ws + 167936);           // 1024 B

  k_setup<<<dim3(256), dim3(256), 0, stream>>>(Wq, Wk, Wv, Wo, bq, bv, bo,
                                               WkqF, WvoF, bvo);
  k_attn<<<dim3(1024, 8), dim3(NTHR), LDS_TOTAL, stream>>>(
      ste_dec, ste_enc, enc, WkqF, WvoF, bvo, out);
}

// Round 7
// 811.109 us; speedup vs baseline: 2.3375x; 2.3375x over previous
//
#include <hip/hip_runtime.h>
#include <stdint.h>

typedef unsigned short u16;
typedef unsigned int u32;
typedef __attribute__((ext_vector_type(8))) short short8;   // 8 bf16 (4 VGPR)
typedef __attribute__((ext_vector_type(4))) float f32x4;

#define NTHR 384
#define K2E16 0.09016844005556021f   /* log2(e)/16 : 1/sqrt(256) folded into exp2 */

// LDS map (64384 B total -> 2 blocks/CU):
//   chL  [36864] : WkqF staged (P1) -> WvoF 32K chunks (P2b) -> fragB (P6b)
//   kwL  [26112] : KW bf16 [96][272B] (P1..P2) -> fragA (P5a..P6a)
//   biasL f32[96], bvoL f32[256]
#define CH_OFF    0
#define KW_OFF    36864
#define KW_STRIDE 272
#define BIAS_OFF  62976
#define BVO_OFF   63360
#define LDS_TOTAL 64384

static __device__ __forceinline__ u16 f2bf(float f) {
  union { float f; u32 u; } v; v.f = f;
  u32 r = v.u + 0x7FFFu + ((v.u >> 16) & 1u);   // RNE
  return (u16)(r >> 16);
}

// ---------------------------------------------------------------------------
// K0: weight prep.
//  - WkqE[de][c]: c<128 -> sum_h Wk[de][h]*Wq[c][h]; c==128 -> Wk[de]·bq;
//                 129..143 -> 0. bf16 MFMA B-frags (K=128, 9 col-tiles).
//    (bk-dependent score terms are constant over p -> cancel in softmax.)
//  - WvoF = bf16 B-frags of Wv@Wo, reordered nt-group-major:
//      idx = (((nt>>2)*8 + kt)*4 + (nt&3))*64*8 + lane*8 + e
//    so each 4-nt group is a contiguous 32KB chunk (LDS-stageable).
//  - bvo = bv@Wo + bo (f32).
// ---------------------------------------------------------------------------
__global__ __launch_bounds__(256) void k_setup(
    const float* __restrict__ Wq, const float* __restrict__ Wk,
    const float* __restrict__ Wv, const float* __restrict__ Wo,
    const float* __restrict__ bq,
    const float* __restrict__ bv, const float* __restrict__ bo,
    u16* __restrict__ WkqF, u16* __restrict__ WvoF, float* __restrict__ bvo) {
  const int ci = blockIdx.x;   // k-row
  const int co = threadIdx.x;  // col
  float acc = 0.f;
  for (int h = 0; h < 256; ++h) acc += Wv[ci*256 + h] * Wo[h*256 + co];
  const int kt = ci >> 5, nt = co >> 4;
  const int lanepart = ((ci >> 3) & 3)*16 + (co & 15), e = ci & 7;
  const int idxv = ((((nt >> 2)*8 + kt)*4 + (nt & 3))*64 + lanepart)*8 + e;
  WvoF[idxv] = f2bf(acc);
  if (ci < 128 && co < 144) {
    float a = 0.f;
    if (co < 128)       { for (int h = 0; h < 256; ++h) a += Wk[ci*256 + h] * Wq[co*256 + h]; }
    else if (co == 128) { for (int h = 0; h < 256; ++h) a += Wk[ci*256 + h] * bq[h]; }
    const int idx = ((((ci >> 5)*9 + (co >> 4))*64) + lanepart)*8 + e;
    WkqF[idx] = f2bf(a);
  }
  if (ci == 0) {
    float a2 = 0.f;
    for (int h = 0; h < 256; ++h) a2 += bv[h] * Wo[h*256 + co];
    bvo[co] = a2 + bo[co];
  }
}

// ---------------------------------------------------------------------------
// K2 fused, grid (1024, 8), 6 waves, 64384B LDS (2 blocks/CU), no spills.
// M-partition: wave w owns rows [16w,16w+16) of every per-(b,n) matrix.
//   P0: issue sd/se reg loads; stage WkqF -> chL (coalesced, once per block)
//   P1: KW = bf16(senc_rows)@WkqE -> kwL (B-frags from LDS); col128 -> biasL
//   P2: issue enc reg loads; scoresT = KW@sdecT + bias; softmax; af pack
//   P2b: enc2 = enc_rows@Wvo, acc2[16]; WvoF in 4x32KB LDS chunks via chL
//   P5/P6: acc2 -> sigma B-frags (halves in kwL then chL); PV; +bvo; store
// ---------------------------------------------------------------------------
__global__ __launch_bounds__(NTHR, 3) void k_attn(
    const float* __restrict__ sdec, const float* __restrict__ senc,
    const float* __restrict__ enc,
    const u16* __restrict__ WkqF, const u16* __restrict__ WvoF,
    const float* __restrict__ bvo, float* __restrict__ out) {
  extern __shared__ char smem[];
  char* chL    = smem + CH_OFF;
  char* kwL    = smem + KW_OFF;
  float* biasL = (float*)(smem + BIAS_OFF);
  float* bvoL  = (float*)(smem + BVO_OFF);

  const int n = blockIdx.x, b = blockIdx.y;
  const int tid = threadIdx.x, wave = tid >> 6, lane = tid & 63;
  const int g = lane >> 4, c15 = lane & 15;
  const int prow = 16*wave + c15;      // this wave's A-fragment row

  // ---- P0: issue sdec/senc reg loads; stage WkqF into chL ----
  const float* sdp = sdec + ((size_t)((b*96 + prow)*1024 + n))*128 + 8*g;
  const float* sep = senc + ((size_t)((b*96 + prow)*1024 + n))*128 + 8*g;
  float4 sdv[4][2], sev[4][2];
  #pragma unroll
  for (int kt = 0; kt < 4; ++kt) {
    sev[kt][0] = *(const float4*)(sep + 32*kt);
    sev[kt][1] = *(const float4*)(sep + 32*kt + 4);
    sdv[kt][0] = *(const float4*)(sdp + 32*kt);
    sdv[kt][1] = *(const float4*)(sdp + 32*kt + 4);
  }
  {
    const f32x4* wsrc = (const f32x4*)WkqF;   // 2304 x 16B
    f32x4* wdst = (f32x4*)chL;
    #pragma unroll
    for (int i = 0; i < 6; ++i) wdst[tid + 384*i] = wsrc[tid + 384*i];
  }
  if (tid < 256) bvoL[tid] = bvo[tid];
  __syncthreads();   // bar: wkq staged

  short8 sef[4], sdf[4];
  #pragma unroll
  for (int kt = 0; kt < 4; ++kt) {
    union { u32 u[4]; short8 v; } cv;
    cv.u[0] = (u32)f2bf(sev[kt][0].x) | ((u32)f2bf(sev[kt][0].y) << 16);
    cv.u[1] = (u32)f2bf(sev[kt][0].z) | ((u32)f2bf(sev[kt][0].w) << 16);
    cv.u[2] = (u32)f2bf(sev[kt][1].x) | ((u32)f2bf(sev[kt][1].y) << 16);
    cv.u[3] = (u32)f2bf(sev[kt][1].z) | ((u32)f2bf(sev[kt][1].w) << 16);
    sef[kt] = cv.v;
  }
  #pragma unroll
  for (int kt = 0; kt < 4; ++kt) {
    union { u32 u[4]; short8 v; } cv;
    cv.u[0] = (u32)f2bf(sdv[kt][0].x) | ((u32)f2bf(sdv[kt][0].y) << 16);
    cv.u[1] = (u32)f2bf(sdv[kt][0].z) | ((u32)f2bf(sdv[kt][0].w) << 16);
    cv.u[2] = (u32)f2bf(sdv[kt][1].x) | ((u32)f2bf(sdv[kt][1].y) << 16);
    cv.u[3] = (u32)f2bf(sdv[kt][1].z) | ((u32)f2bf(sdv[kt][1].w) << 16);
    sdf[kt] = cv.v;
  }

  // ---- P1: KW rows [16w,16w+16) x 144 = senc_rows @ WkqE (B from LDS) ----
  {
    f32x4 acc[9];
    #pragma unroll
    for (int nt = 0; nt < 9; ++nt) acc[nt] = (f32x4)0.f;
    #pragma unroll
    for (int kt = 0; kt < 4; ++kt) {
      #pragma unroll
      for (int nt = 0; nt < 9; ++nt) {
        const short8 bf = *(const short8*)(chL + ((kt*9 + nt)*64 + lane)*16);
        acc[nt] = __builtin_amdgcn_mfma_f32_16x16x32_bf16(sef[kt], bf, acc[nt], 0, 0, 0);
      }
    }
    #pragma unroll
    for (int nt = 0; nt < 8; ++nt) {
      #pragma unroll
      for (int r = 0; r < 4; ++r)
        *(u16*)(kwL + (16*wave + 4*g + r)*KW_STRIDE + 2*(c15 + 16*nt)) = f2bf(acc[nt][r]);
    }
    if (c15 == 0) {
      #pragma unroll
      for (int r = 0; r < 4; ++r) biasL[16*wave + 4*g + r] = acc[8][r];
    }
  }
  __syncthreads();   // bar: kwL+biasL ready; chL reads done

  // ---- issue enc reg loads (consumed in P2b; fly during P2) ----
  const float* ep = enc + ((size_t)((b*96 + prow)*1024 + n))*256 + 8*g;
  float4 ev[8][2];
  #pragma unroll
  for (int kt = 0; kt < 8; ++kt) {
    ev[kt][0] = *(const float4*)(ep + 32*kt);
    ev[kt][1] = *(const float4*)(ep + 32*kt + 4);
  }

  // ---- P2: scoresT = KW[:,0:128] @ sdecT + bias; softmax; af pack ----
  f32x4 sac[6];
  #pragma unroll
  for (int pt = 0; pt < 6; ++pt) sac[pt] = (f32x4)0.f;
  #pragma unroll
  for (int kt = 0; kt < 4; ++kt) {
    #pragma unroll
    for (int pt = 0; pt < 6; ++pt) {
      const short8 kf = *(const short8*)(kwL + (16*pt + c15)*KW_STRIDE + 16*g + 64*kt);
      sac[pt] = __builtin_amdgcn_mfma_f32_16x16x32_bf16(kf, sdf[kt], sac[pt], 0, 0, 0);
    }
  }
  #pragma unroll
  for (int pt = 0; pt < 6; ++pt)
    #pragma unroll
    for (int r = 0; r < 4; ++r)
      sac[pt][r] += biasL[16*pt + 4*g + r];

  float m = sac[0][0];
  #pragma unroll
  for (int pt = 0; pt < 6; ++pt)
    #pragma unroll
    for (int r = 0; r < 4; ++r) m = fmaxf(m, sac[pt][r]);
  m = fmaxf(m, __shfl_xor(m, 16));
  m = fmaxf(m, __shfl_xor(m, 32));
  float s = 0.f;
  #pragma unroll
  for (int pt = 0; pt < 6; ++pt)
    #pragma unroll
    for (int r = 0; r < 4; ++r) {
      const float e = exp2f((sac[pt][r] - m) * K2E16);
      sac[pt][r] = e; s += e;
    }
  s += __shfl_xor(s, 16);
  s += __shfl_xor(s, 32);
  const float rs = 1.f / s;

  short8 af[3];
  #pragma unroll
  for (int kb = 0; kb < 3; ++kb) {
    union { u32 u[4]; short8 v; } cv;
    cv.u[0] = (u32)f2bf(sac[2*kb][0]*rs)   | ((u32)f2bf(sac[2*kb][1]*rs)   << 16);
    cv.u[1] = (u32)f2bf(sac[2*kb][2]*rs)   | ((u32)f2bf(sac[2*kb][3]*rs)   << 16);
    cv.u[2] = (u32)f2bf(sac[2*kb+1][0]*rs) | ((u32)f2bf(sac[2*kb+1][1]*rs) << 16);
    cv.u[3] = (u32)f2bf(sac[2*kb+1][2]*rs) | ((u32)f2bf(sac[2*kb+1][3]*rs) << 16);
    af[kb] = cv.v;
  }

  // ---- P2b: enc2 = enc_rows @ Wvo; WvoF via 4 x 32KB LDS chunks ----
  f32x4 acc2[16];
  #pragma unroll
  for (int nt = 0; nt < 16; ++nt) acc2[nt] = (f32x4)0.f;
  #pragma unroll
  for (int c = 0; c < 4; ++c) {
    {
      const f32x4* csrc = (const f32x4*)(WvoF + (size_t)c*16384);  // u16 units
      f32x4* cdst = (f32x4*)chL;
      #pragma unroll
      for (int i = 0; i < 5; ++i) cdst[tid + 384*i] = csrc[tid + 384*i];
      if (tid < 128) cdst[1920 + tid] = csrc[1920 + tid];
    }
    __syncthreads();   // chunk staged
    #pragma unroll
    for (int kt = 0; kt < 8; ++kt) {
      union { u32 u[4]; short8 v; } cv;
      cv.u[0] = (u32)f2bf(ev[kt][0].x) | ((u32)f2bf(ev[kt][0].y) << 16);
      cv.u[1] = (u32)f2bf(ev[kt][0].z) | ((u32)f2bf(ev[kt][0].w) << 16);
      cv.u[2] = (u32)f2bf(ev[kt][1].x) | ((u32)f2bf(ev[kt][1].y) << 16);
      cv.u[3] = (u32)f2bf(ev[kt][1].z) | ((u32)f2bf(ev[kt][1].w) << 16);
      const short8 a = cv.v;
      #pragma unroll
      for (int ntl = 0; ntl < 4; ++ntl) {
        const short8 bf = *(const short8*)(chL + ((kt*4 + ntl)*64 + lane)*16);
        acc2[c*4 + ntl] = __builtin_amdgcn_mfma_f32_16x16x32_bf16(a, bf, acc2[c*4 + ntl], 0, 0, 0);
      }
    }
    __syncthreads();   // chunk reads done -> chL free for next stage / frags
  }

  // ---- P5/P6: sigma frag exchange + PV + store, two col-halves ----
  const int kb0 = wave >> 1, hi = wave & 1;
  // P5a: nt 0..7 frags -> kwL region (dead after P2)
  #pragma unroll
  for (int ntl = 0; ntl < 8; ++ntl) {
    uint2 o;
    const f32x4 v = acc2[ntl];
    o.x = (u32)f2bf(v[0]) | ((u32)f2bf(v[1]) << 16);
    o.y = (u32)f2bf(v[2]) | ((u32)f2bf(v[3]) << 16);
    *(uint2*)(kwL + (((ntl*3 + kb0)*64 + lane) << 4) + hi*8) = o;
  }
  __syncthreads();   // fragA ready
  // P5b: nt 8..15 frags -> chL region (concurrent with P6a reads of kwL)
  #pragma unroll
  for (int ntl = 0; ntl < 8; ++ntl) {
    uint2 o;
    const f32x4 v = acc2[8 + ntl];
    o.x = (u32)f2bf(v[0]) | ((u32)f2bf(v[1]) << 16);
    o.y = (u32)f2bf(v[2]) | ((u32)f2bf(v[3]) << 16);
    *(uint2*)(chL + (((ntl*3 + kb0)*64 + lane) << 4) + hi*8) = o;
  }
  // P6a: PV cols 0..127
  #pragma unroll
  for (int ntl = 0; ntl < 8; ++ntl) {
    f32x4 oa = (f32x4)0.f;
    #pragma unroll
    for (int kb = 0; kb < 3; ++kb) {
      const short8 ef = *(const short8*)(kwL + (((ntl*3 + kb)*64 + lane) << 4));
      oa = __builtin_amdgcn_mfma_f32_16x16x32_bf16(af[kb], ef, oa, 0, 0, 0);
    }
    const int c = c15 + 16*ntl;
    const float bz = bvoL[c];
    #pragma unroll
    for (int r = 0; r < 4; ++r) {
      const int qi = 16*wave + 4*g + r;
      out[((size_t)((b*96 + qi)*1024 + n))*256 + c] = oa[r] + bz;
    }
  }
  __syncthreads();   // fragB ready
  // P6b: PV cols 128..255
  #pragma unroll
  for (int ntl = 0; ntl < 8; ++ntl) {
    f32x4 oa = (f32x4)0.f;
    #pragma unroll
    for (int kb = 0; kb < 3; ++kb) {
      const short8 ef = *(const short8*)(chL + (((ntl*3 + kb)*64 + lane) << 4));
      oa = __builtin_amdgcn_mfma_f32_16x16x32_bf16(af[kb], ef, oa, 0, 0, 0);
    }
    const int c = c15 + 16*(8 + ntl);
    const float bz = bvoL[c];
    #pragma unroll
    for (int r = 0; r < 4; ++r) {
      const int qi = 16*wave + 4*g + r;
      out[((size_t)((b*96 + qi)*1024 + n))*256 + c] = oa[r] + bz;
    }
  }
}

// ---------------------------------------------------------------------------
extern "C" void kernel_launch(void* const* d_in, const int* in_sizes, int n_in,
                              void* d_out, int out_size, void* d_ws, size_t ws_size,
                              hipStream_t stream) {
  const float* enc     = (const float*)d_in[0];
  const float* ste_enc = (const float*)d_in[1];
  const float* ste_dec = (const float*)d_in[2];
  const float* Wq = (const float*)d_in[3];
  const float* bq = (const float*)d_in[4];
  const float* Wk = (const float*)d_in[5];
  const float* Wv = (const float*)d_in[7];
  const float* bv = (const float*)d_in[8];
  const float* Wo = (const float*)d_in[9];
  const float* bo = (const float*)d_in[10];
  float* out = (float*)d_out;

  u16*   WkqF = (u16*)d_ws;                               // 36864 B
  u16*   WvoF = (u16*)((char*)d_ws + 36864);              // 131072 B -> 167936
  float* bvo  = (float*)((char*)d_ws + 167936);           // 1024 B

  k_setup<<<dim3(256), dim3(256), 0, stream>>>(Wq, Wk, Wv, Wo, bq, bv, bo,
                                               WkqF, WvoF, bvo);
  k_attn<<<dim3(1024, 8), dim3(NTHR), LDS_TOTAL, stream>>>(
      ste_dec, ste_enc, enc, WkqF, WvoF, bvo, out);
}

// Round 8
// 684.495 us; speedup vs baseline: 2.7698x; 1.1850x over previous
//
#include <hip/hip_runtime.h>
#include <stdint.h>

typedef unsigned short u16;
typedef unsigned int u32;
typedef __attribute__((ext_vector_type(8))) short short8;   // 8 bf16 (4 VGPR)
typedef __attribute__((ext_vector_type(4))) float f32x4;

#define NTHR 384
#define K2E16 0.09016844005556021f   /* log2(e)/16 : 1/sqrt(256) folded into exp2 */

// LDS map (60288 B total):
//   wvoL  [0, 32768)  : Wvo per-kt 16KB chunks, double-buffered; later fragB (24576)
//   kwL   [32768, 58880): KW bf16 [96][272B] (26112); later fragA (24576)
//   biasL f32[96] @58880, bvoL f32[256] @59264
#define KW_OFF    32768
#define KW_STRIDE 272
#define BIAS_OFF  58880
#define BVO_OFF   59264
#define LDS_TOTAL 60288

static __device__ __forceinline__ u16 f2bf(float f) {
  union { float f; u32 u; } v; v.f = f;
  u32 r = v.u + 0x7FFFu + ((v.u >> 16) & 1u);   // RNE
  return (u16)(r >> 16);
}

// ---------------------------------------------------------------------------
// K0: weight prep.
//  - WkqE[de][c]: c<128 -> sum_h Wk[de][h]*Wq[c][h]; c==128 -> Wk[de]·bq;
//                 129..143 -> 0. bf16 MFMA B-frags (K=128, 9 col-tiles).
//    (bk-dependent score terms are constant over p -> cancel in softmax.)
//  - WvoF = bf16 B-frags of Wv@Wo, frag index (kt*16+nt): each kt's 16 nt
//    are a contiguous 16KB chunk (LDS-stageable per-kt).
//  - bvo = bv@Wo + bo (f32).
// ---------------------------------------------------------------------------
__global__ __launch_bounds__(256) void k_setup(
    const float* __restrict__ Wq, const float* __restrict__ Wk,
    const float* __restrict__ Wv, const float* __restrict__ Wo,
    const float* __restrict__ bq,
    const float* __restrict__ bv, const float* __restrict__ bo,
    u16* __restrict__ WkqF, u16* __restrict__ WvoF, float* __restrict__ bvo) {
  const int ci = blockIdx.x;   // k-row
  const int co = threadIdx.x;  // col
  float acc = 0.f;
  for (int h = 0; h < 256; ++h) acc += Wv[ci*256 + h] * Wo[h*256 + co];
  const int lanepart = ((ci >> 3) & 3)*16 + (co & 15), e = ci & 7;
  const int idxv = (((ci >> 5)*16 + (co >> 4))*64 + lanepart)*8 + e;
  WvoF[idxv] = f2bf(acc);
  if (ci < 128 && co < 144) {
    float a = 0.f;
    if (co < 128)       { for (int h = 0; h < 256; ++h) a += Wk[ci*256 + h] * Wq[co*256 + h]; }
    else if (co == 128) { for (int h = 0; h < 256; ++h) a += Wk[ci*256 + h] * bq[h]; }
    const int idx = (((ci >> 5)*9 + (co >> 4))*64 + lanepart)*8 + e;
    WkqF[idx] = f2bf(a);
  }
  if (ci == 0) {
    float a2 = 0.f;
    for (int h = 0; h < 256; ++h) a2 += bv[h] * Wo[h*256 + co];
    bvo[co] = a2 + bo[co];
  }
}

// ---------------------------------------------------------------------------
// K2 fused, grid (1024, 8), 6 waves, 60288B LDS.
// M-partition: wave w owns rows [16w,16w+16) of every per-(b,n) matrix.
//   P0: issue sd/se reg loads + Wvo chunk0 loads; biases
//   P1: KW = bf16(senc_rows)@WkqE -> kwL (B-frags DIRECT global, L1-hot);
//       col128 -> biasL; chunk0 -> wvoL.buf0
//   P2: issue enc reg loads; scoresT = KW@sdecT + bias; softmax; af pack
//   P2b: 8x per-kt: {prefetch chunk kt+1; 16 MFMA from buf[kt&1];
//        ds_write chunk kt+1 -> buf[(kt+1)&1]; barrier}
//   P5: acc2 -> sigma B-frags, fragA over kwL + fragB over wvoL, one sync
//   P6: out = attn@enc2 + bvo (16 col-tiles), f32 stores
// ---------------------------------------------------------------------------
__global__ __launch_bounds__(NTHR, 3) void k_attn(
    const float* __restrict__ sdec, const float* __restrict__ senc,
    const float* __restrict__ enc,
    const u16* __restrict__ WkqF, const u16* __restrict__ WvoF,
    const float* __restrict__ bvo, float* __restrict__ out) {
  extern __shared__ char smem[];
  char* wvoL   = smem;
  char* kwL    = smem + KW_OFF;
  char* fragA  = smem + KW_OFF;    // 24576 over kwL (P5+)
  char* fragB  = smem;             // 24576 over wvoL (P5+)
  float* biasL = (float*)(smem + BIAS_OFF);
  float* bvoL  = (float*)(smem + BVO_OFF);

  const int n = blockIdx.x, b = blockIdx.y;
  const int tid = threadIdx.x, wave = tid >> 6, lane = tid & 63;
  const int g = lane >> 4, c15 = lane & 15;
  const int prow = 16*wave + c15;      // this wave's A-fragment row

  // ---- P0: issue sdec/senc reg loads + Wvo chunk0 loads ----
  const float* sdp = sdec + ((size_t)((b*96 + prow)*1024 + n))*128 + 8*g;
  const float* sep = senc + ((size_t)((b*96 + prow)*1024 + n))*128 + 8*g;
  float4 sdv[4][2], sev[4][2];
  #pragma unroll
  for (int kt = 0; kt < 4; ++kt) {
    sev[kt][0] = *(const float4*)(sep + 32*kt);
    sev[kt][1] = *(const float4*)(sep + 32*kt + 4);
    sdv[kt][0] = *(const float4*)(sdp + 32*kt);
    sdv[kt][1] = *(const float4*)(sdp + 32*kt + 4);
  }
  const f32x4* wv = (const f32x4*)WvoF;   // chunk kt = wv + kt*1024 (16KB)
  f32x4 c0[3];
  #pragma unroll
  for (int i = 0; i < 3; ++i) {
    const int idx = tid + 384*i;
    if (idx < 1024) c0[i] = wv[idx];
  }
  if (tid < 256) bvoL[tid] = bvo[tid];

  short8 sef[4], sdf[4];
  #pragma unroll
  for (int kt = 0; kt < 4; ++kt) {
    union { u32 u[4]; short8 v; } cv;
    cv.u[0] = (u32)f2bf(sev[kt][0].x) | ((u32)f2bf(sev[kt][0].y) << 16);
    cv.u[1] = (u32)f2bf(sev[kt][0].z) | ((u32)f2bf(sev[kt][0].w) << 16);
    cv.u[2] = (u32)f2bf(sev[kt][1].x) | ((u32)f2bf(sev[kt][1].y) << 16);
    cv.u[3] = (u32)f2bf(sev[kt][1].z) | ((u32)f2bf(sev[kt][1].w) << 16);
    sef[kt] = cv.v;
  }
  #pragma unroll
  for (int kt = 0; kt < 4; ++kt) {
    union { u32 u[4]; short8 v; } cv;
    cv.u[0] = (u32)f2bf(sdv[kt][0].x) | ((u32)f2bf(sdv[kt][0].y) << 16);
    cv.u[1] = (u32)f2bf(sdv[kt][0].z) | ((u32)f2bf(sdv[kt][0].w) << 16);
    cv.u[2] = (u32)f2bf(sdv[kt][1].x) | ((u32)f2bf(sdv[kt][1].y) << 16);
    cv.u[3] = (u32)f2bf(sdv[kt][1].z) | ((u32)f2bf(sdv[kt][1].w) << 16);
    sdf[kt] = cv.v;
  }

  // ---- P1: KW rows [16w,16w+16) x 144 = senc_rows @ WkqE (B direct global) ----
  {
    f32x4 acc[9];
    #pragma unroll
    for (int nt = 0; nt < 9; ++nt) acc[nt] = (f32x4)0.f;
    #pragma unroll
    for (int kt = 0; kt < 4; ++kt) {
      #pragma unroll
      for (int nt = 0; nt < 9; ++nt) {
        const short8 bf = *(const short8*)(WkqF + (size_t)((kt*9 + nt)*64 + lane)*8);
        acc[nt] = __builtin_amdgcn_mfma_f32_16x16x32_bf16(sef[kt], bf, acc[nt], 0, 0, 0);
      }
    }
    #pragma unroll
    for (int nt = 0; nt < 8; ++nt) {
      #pragma unroll
      for (int r = 0; r < 4; ++r)
        *(u16*)(kwL + (16*wave + 4*g + r)*KW_STRIDE + 2*(c15 + 16*nt)) = f2bf(acc[nt][r]);
    }
    if (c15 == 0) {
      #pragma unroll
      for (int r = 0; r < 4; ++r) biasL[16*wave + 4*g + r] = acc[8][r];
    }
  }
  // commit Wvo chunk0 -> buf0
  {
    f32x4* b0 = (f32x4*)wvoL;
    #pragma unroll
    for (int i = 0; i < 3; ++i) {
      const int idx = tid + 384*i;
      if (idx < 1024) b0[idx] = c0[i];
    }
  }
  __syncthreads();   // bar1: kwL + biasL + chunk0 ready

  // ---- issue enc reg loads (consumed per-kt in P2b; fly during P2) ----
  const float* ep = enc + ((size_t)((b*96 + prow)*1024 + n))*256 + 8*g;
  float4 ev[8][2];
  #pragma unroll
  for (int kt = 0; kt < 8; ++kt) {
    ev[kt][0] = *(const float4*)(ep + 32*kt);
    ev[kt][1] = *(const float4*)(ep + 32*kt + 4);
  }

  // ---- P2: scoresT = KW[:,0:128] @ sdecT + bias; softmax; af pack ----
  f32x4 sac[6];
  #pragma unroll
  for (int pt = 0; pt < 6; ++pt) sac[pt] = (f32x4)0.f;
  #pragma unroll
  for (int kt = 0; kt < 4; ++kt) {
    #pragma unroll
    for (int pt = 0; pt < 6; ++pt) {
      const short8 kf = *(const short8*)(kwL + (16*pt + c15)*KW_STRIDE + 16*g + 64*kt);
      sac[pt] = __builtin_amdgcn_mfma_f32_16x16x32_bf16(kf, sdf[kt], sac[pt], 0, 0, 0);
    }
  }
  #pragma unroll
  for (int pt = 0; pt < 6; ++pt)
    #pragma unroll
    for (int r = 0; r < 4; ++r)
      sac[pt][r] += biasL[16*pt + 4*g + r];

  float m = sac[0][0];
  #pragma unroll
  for (int pt = 0; pt < 6; ++pt)
    #pragma unroll
    for (int r = 0; r < 4; ++r) m = fmaxf(m, sac[pt][r]);
  m = fmaxf(m, __shfl_xor(m, 16));
  m = fmaxf(m, __shfl_xor(m, 32));
  float s = 0.f;
  #pragma unroll
  for (int pt = 0; pt < 6; ++pt)
    #pragma unroll
    for (int r = 0; r < 4; ++r) {
      const float e = exp2f((sac[pt][r] - m) * K2E16);
      sac[pt][r] = e; s += e;
    }
  s += __shfl_xor(s, 16);
  s += __shfl_xor(s, 32);
  const float rs = 1.f / s;

  short8 af[3];
  #pragma unroll
  for (int kb = 0; kb < 3; ++kb) {
    union { u32 u[4]; short8 v; } cv;
    cv.u[0] = (u32)f2bf(sac[2*kb][0]*rs)   | ((u32)f2bf(sac[2*kb][1]*rs)   << 16);
    cv.u[1] = (u32)f2bf(sac[2*kb][2]*rs)   | ((u32)f2bf(sac[2*kb][3]*rs)   << 16);
    cv.u[2] = (u32)f2bf(sac[2*kb+1][0]*rs) | ((u32)f2bf(sac[2*kb+1][1]*rs) << 16);
    cv.u[3] = (u32)f2bf(sac[2*kb+1][2]*rs) | ((u32)f2bf(sac[2*kb+1][3]*rs) << 16);
    af[kb] = cv.v;
  }

  // ---- P2b: enc2 = enc_rows @ Wvo; per-kt 16KB chunks, double-buffered ----
  f32x4 acc2[16];
  #pragma unroll
  for (int nt = 0; nt < 16; ++nt) acc2[nt] = (f32x4)0.f;
  #pragma unroll
  for (int kt = 0; kt < 8; ++kt) {
    // prefetch next chunk to regs (flies under this kt's MFMAs)
    f32x4 nx[3];
    if (kt < 7) {
      const f32x4* src = wv + (kt + 1)*1024;
      #pragma unroll
      for (int i = 0; i < 3; ++i) {
        const int idx = tid + 384*i;
        if (idx < 1024) nx[i] = src[idx];
      }
    }
    // convert this kt's enc A-frag
    union { u32 u[4]; short8 v; } cv;
    cv.u[0] = (u32)f2bf(ev[kt][0].x) | ((u32)f2bf(ev[kt][0].y) << 16);
    cv.u[1] = (u32)f2bf(ev[kt][0].z) | ((u32)f2bf(ev[kt][0].w) << 16);
    cv.u[2] = (u32)f2bf(ev[kt][1].x) | ((u32)f2bf(ev[kt][1].y) << 16);
    cv.u[3] = (u32)f2bf(ev[kt][1].z) | ((u32)f2bf(ev[kt][1].w) << 16);
    const short8 a = cv.v;
    const char* buf = wvoL + (kt & 1)*16384;
    #pragma unroll
    for (int nt = 0; nt < 16; ++nt) {
      const short8 bf = *(const short8*)(buf + ((nt*64 + lane) << 4));
      acc2[nt] = __builtin_amdgcn_mfma_f32_16x16x32_bf16(a, bf, acc2[nt], 0, 0, 0);
    }
    // commit next chunk to the other buffer (safe: its readers synced last iter)
    if (kt < 7) {
      f32x4* bw = (f32x4*)(wvoL + ((kt + 1) & 1)*16384);
      #pragma unroll
      for (int i = 0; i < 3; ++i) {
        const int idx = tid + 384*i;
        if (idx < 1024) bw[idx] = nx[i];
      }
    }
    __syncthreads();
  }

  // ---- P5: acc2 -> sigma B-frags; fragA (nt 0..7) + fragB (nt 8..15) ----
  const int kb0 = wave >> 1, hi = wave & 1;
  #pragma unroll
  for (int ntl = 0; ntl < 8; ++ntl) {
    uint2 oA, oB;
    const f32x4 vA = acc2[ntl], vB = acc2[8 + ntl];
    oA.x = (u32)f2bf(vA[0]) | ((u32)f2bf(vA[1]) << 16);
    oA.y = (u32)f2bf(vA[2]) | ((u32)f2bf(vA[3]) << 16);
    oB.x = (u32)f2bf(vB[0]) | ((u32)f2bf(vB[1]) << 16);
    oB.y = (u32)f2bf(vB[2]) | ((u32)f2bf(vB[3]) << 16);
    *(uint2*)(fragA + (((ntl*3 + kb0)*64 + lane) << 4) + hi*8) = oA;
    *(uint2*)(fragB + (((ntl*3 + kb0)*64 + lane) << 4) + hi*8) = oB;
  }
  __syncthreads();   // frags ready

  // ---- P6: out = attn @ enc2 + bvo; f32 store ----
  #pragma unroll
  for (int nt = 0; nt < 16; ++nt) {
    const char* fb = (nt < 8) ? fragA : fragB;
    const int ntl = nt & 7;
    f32x4 oa = (f32x4)0.f;
    #pragma unroll
    for (int kb = 0; kb < 3; ++kb) {
      const short8 ef = *(const short8*)(fb + (((ntl*3 + kb)*64 + lane) << 4));
      oa = __builtin_amdgcn_mfma_f32_16x16x32_bf16(af[kb], ef, oa, 0, 0, 0);
    }
    const int c = c15 + 16*nt;
    const float bz = bvoL[c];
    #pragma unroll
    for (int r = 0; r < 4; ++r) {
      const int qi = 16*wave + 4*g + r;
      out[((size_t)((b*96 + qi)*1024 + n))*256 + c] = oa[r] + bz;
    }
  }
}

// ---------------------------------------------------------------------------
extern "C" void kernel_launch(void* const* d_in, const int* in_sizes, int n_in,
                              void* d_out, int out_size, void* d_ws, size_t ws_size,
                              hipStream_t stream) {
  const float* enc     = (const float*)d_in[0];
  const float* ste_enc = (const float*)d_in[1];
  const float* ste_dec = (const float*)d_in[2];
  const float* Wq = (const float*)d_in[3];
  const float* bq = (const float*)d_in[4];
  const float* Wk = (const float*)d_in[5];
  const float* Wv = (const float*)d_in[7];
  const float* bv = (const float*)d_in[8];
  const float* Wo = (const float*)d_in[9];
  const float* bo = (const float*)d_in[10];
  float* out = (float*)d_out;

  u16*   WkqF = (u16*)d_ws;                               // 36864 B
  u16*   WvoF = (u16*)((char*)d_ws + 36864);              // 131072 B -> 167936
  float* bvo  = (float*)((char*)d_ws + 167936);           // 1024 B

  k_setup<<<dim3(256), dim3(256), 0, stream>>>(Wq, Wk, Wv, Wo, bq, bv, bo,
                                               WkqF, WvoF, bvo);
  k_attn<<<dim3(1024, 8), dim3(NTHR), LDS_TOTAL, stream>>>(
      ste_dec, ste_enc, enc, WkqF, WvoF, bvo, out);
}